// Round 8
// baseline (188.119 us; speedup 1.0000x reference)
//
#include <hip/hip_runtime.h>

#define BIGF 1e9f
#define TT 512
#define DD 256
#define NB 64
#define PROWS 580     // per-batch pair-rows (1 d0-row + 511 pairs + 32 prefetch pad + slack)
#define SAK 40        // LDS row stride in bf16 (32 data + 8 pad)
#define CST 66        // C-tile LDS stride in floats
#define NDP 64        // consumer (DP) blocks, blockIdx 0..63
#define NPROD 768     // producer blocks, 2 tiles each
#define CNT_OFF (20 * 1024 * 1024)  // counters past diag (18.2 MB) in the 256 MiB ws

typedef float floatx16 __attribute__((ext_vector_type(16)));
typedef __bf16 bf16x8 __attribute__((ext_vector_type(8)));

// ---------- DPP wave shifts: lane i <- lane i-1 (shr) / lane i+1 (shl); invalid lanes get `oldv`
__device__ __forceinline__ float dpp_wave_shr1(float x, float oldv) {
  int r = __builtin_amdgcn_update_dpp(__builtin_bit_cast(int, oldv),
                                      __builtin_bit_cast(int, x),
                                      0x138, 0xF, 0xF, false);  // WAVE_SHR1
  return __builtin_bit_cast(float, r);
}
__device__ __forceinline__ float dpp_wave_shl1(float x, float oldv) {
  int r = __builtin_amdgcn_update_dpp(__builtin_bit_cast(int, oldv),
                                      __builtin_bit_cast(int, x),
                                      0x130, 0xF, 0xF, false);  // WAVE_SHL1
  return __builtin_bit_cast(float, r);
}

// ---------- pair-interleaved band layout (round-7 verified) ----------
// Cell (d, k) [k = i-j+50, k and d share parity]:
//   row = 1 + ((d-1)>>1); off = row*128 + 2*(k>>1) + ((d-1)&1)
// Pair row p>=1 holds d=2p-1 (even comps) and d=2p (odd comps): one float2 at 2l gives
// lane l both its band cells. d=0 cell (0,0) -> off 51.

// ---------- Fused kernel: 768 producers (cost tiles) + 64 DP consumers, one launch ----------
// ROUND-3 FUSION RETRY with the spill fixed: __launch_bounds__(256,1) lifts the implicit
// high-occupancy VGPR cap (round 3 compiled to 56 VGPR -> DP cr[] and producer state spilled
// to scratch -> 106 us). DP prefetch depth 32 float2 (64 VGPR) + producer ~110 VGPR -> no
// spill, 4 blocks/CU -> all 832 blocks co-resident.
// Producers: round-7 pair-layout cost code verbatim + per-tile agent-RELEASE atomicAdd on
// cnt[b] after tile-end __syncthreads (vmcnt drained -> stores visible; proven in round 3).
// Consumers: block b<64, wave 0 only (waves 1-3 exit; no barriers on this path): spin on
// cnt[b]==24 (relaxed agent + s_sleep), agent ACQUIRE fence, then round-7 zero-shuffle DP.
// Batch-major producer order completes batches progressively -> most DP hides under cost.
// Deadlock-free: producers never wait; 64 spinners can't exhaust residency (capacity 1024).
__global__ __launch_bounds__(256, 1) void dtw_fused(const float* __restrict__ x1,
                                                    const float* __restrict__ x2,
                                                    float* __restrict__ diag,
                                                    unsigned* __restrict__ cnt,
                                                    float* __restrict__ out) {
  __shared__ __align__(16) float sC[64 * CST];

  if (blockIdx.x < NDP) {
    // ================= DP consumer =================
    if (threadIdx.x >= 64) return;  // single wave; no __syncthreads on this path
    const int b = blockIdx.x;       // blockIdx%8 == b%8 -> same XCD as batch b's producers
    const int l = threadIdx.x;

    while (__hip_atomic_load(cnt + b, __ATOMIC_RELAXED, __HIP_MEMORY_SCOPE_AGENT) != 24u)
      __builtin_amdgcn_s_sleep(8);
    __builtin_amdgcn_fence(__ATOMIC_ACQUIRE, "agent");

    const bool inv_odd = (l >= 50);   // k=2l+1 > 100
    const bool inv_even = (l >= 51);  // k=2l   > 100
    const float* base = diag + (size_t)b * (PROWS * 128);

    const float* pP = base + 128 + 2 * l;  // pair 0 (d=1,2), lane slot
    float2 cr[32];                         // 32 pairs = 64 diagonals buffered (64 VGPR)
#pragma unroll
    for (int s = 0; s < 32; ++s) {
      cr[s] = *(const float2*)pP;
      pP += 128;
    }

    float prev2 = BIGF;
    const float c00 = base[51];  // cell (0,0)
    float prev1 = (l == 25) ? c00 : BIGF;
    float ans = BIGF;

    for (int o = 0; o < 16; ++o) {
#pragma unroll
      for (int u = 0; u < 32; ++u) {  // pair p = 32*o + u; static slot index (rule #20)
        const float2 v = cr[u];
        cr[u] = *(const float2*)pP;   // prefetch pair p+32 (max row 544 < PROWS, in-batch)
        pP += 128;
        // odd diagonal d = 2p+1
        const float c1 = inv_odd ? BIGF : v.x;
        const float sh = dpp_wave_shl1(prev1, BIGF);
        const float m3 = fminf(fminf(prev1, sh), prev2);
        prev2 = prev1;
        prev1 = c1 + m3;
        // even diagonal d = 2p+2
        const float c2 = inv_even ? BIGF : v.y;
        const float sh2 = dpp_wave_shr1(prev1, BIGF);
        const float m32 = fminf(fminf(sh2, prev1), prev2);
        prev2 = prev1;
        prev1 = c2 + m32;
        if (o == 15 && u == 30) ans = prev1;  // pair 510 even step -> d=1022, cell (511,511)
        // pair 511 consumed after ans; poison/paint values finite -> harmless
      }
    }
    if (l == 25) out[b] = ans;
    return;
  }

  // ================= producer (round-7 cost path verbatim) =================
  const int p = blockIdx.x - NDP;  // 0..767
  const int x = p & 7;             // XCD affinity heuristic (perf only)
  const int pl = p >> 3;           // 0..95 within XCD

  __bf16* sA = (__bf16*)sC;
  __bf16* sB = ((__bf16*)sC) + 64 * SAK;
  __shared__ float rA[64];
  __shared__ float rB[64];

  const int t = threadIdx.x;
  const int lane = t & 63;
  const int w = t >> 6;
  const int wi = w >> 1;
  const int wj = w & 1;
  const int ln = lane & 31;
  const int kh = lane >> 5;

  const int sr = t >> 2;
  const int sq = t & 3;
  __bf16* dA = sA + sr * SAK + sq * 8;
  __bf16* dB = sB + sr * SAK + sq * 8;
  const __bf16* fAp = sA + (wi * 32 + ln) * SAK + kh * 8;
  const __bf16* fBp = sB + (wj * 32 + ln) * SAK + kh * 8;

  for (int kt = 0; kt < 2; ++kt) {
    const int T = pl + 96 * kt;     // 0..191, batch-major within XCD
    const int bhi = T / 24;
    const int m = T - bhi * 24;
    const int b = bhi * 8 + x;
    const int it = m & 7;
    const int jt = m >> 3;
    const int i0 = it * 64;
    const int j0 = i0 - 50 + jt * 64;

    float* db = diag + (size_t)b * (PROWS * 128);

    // corner paint: consumed-but-unwritten cells of d in [1,64) U [972,1025) get BIG
    if (m == 0) {
      for (int r = w; r < 116; r += 4) {
        const int d = (r < 63) ? (r + 1) : (909 + r);  // 1..63, 972..1024
        const int pp = d & 1;
        const int k = 2 * lane + pp;
        const int i = (d + k - 50) >> 1;
        const int j = d - i;
        if (k > 100 || (unsigned)i >= TT || (unsigned)j >= TT)
          db[(size_t)(1 + ((d - 1) >> 1)) * 128 + 2 * lane + ((d - 1) & 1)] = BIGF;
      }
    }

    const float* x1b = x1 + (size_t)b * (TT * DD);
    const float* x2b = x2 + (size_t)b * (TT * DD);
    int gj = j0 + sr;
    gj = gj < 0 ? 0 : (gj > TT - 1 ? TT - 1 : gj);
    const float* pAg = x1b + (size_t)(i0 + sr) * DD + sq * 8;
    const float* pBg = x2b + (size_t)gj * DD + sq * 8;

    floatx16 acc = {};
    float pa = 0.f, pb = 0.f;

    for (int kc = 0; kc < DD; kc += 32) {
      const float4 a0 = *(const float4*)(pAg + kc);
      const float4 a1 = *(const float4*)(pAg + kc + 4);
      const float4 b0 = *(const float4*)(pBg + kc);
      const float4 b1 = *(const float4*)(pBg + kc + 4);
      pa += a0.x * a0.x + a0.y * a0.y + a0.z * a0.z + a0.w * a0.w;
      pa += a1.x * a1.x + a1.y * a1.y + a1.z * a1.z + a1.w * a1.w;
      pb += b0.x * b0.x + b0.y * b0.y + b0.z * b0.z + b0.w * b0.w;
      pb += b1.x * b1.x + b1.y * b1.y + b1.z * b1.z + b1.w * b1.w;
      // barrier also fences the previous tile's sC reads before sA/sB overwrite (alias)
      __syncthreads();
      {
        bf16x8 va, vb;
        va[0] = (__bf16)a0.x; va[1] = (__bf16)a0.y; va[2] = (__bf16)a0.z; va[3] = (__bf16)a0.w;
        va[4] = (__bf16)a1.x; va[5] = (__bf16)a1.y; va[6] = (__bf16)a1.z; va[7] = (__bf16)a1.w;
        vb[0] = (__bf16)b0.x; vb[1] = (__bf16)b0.y; vb[2] = (__bf16)b0.z; vb[3] = (__bf16)b0.w;
        vb[4] = (__bf16)b1.x; vb[5] = (__bf16)b1.y; vb[6] = (__bf16)b1.z; vb[7] = (__bf16)b1.w;
        *(bf16x8*)dA = va;
        *(bf16x8*)dB = vb;
      }
      __syncthreads();
      const bf16x8 fa0 = *(const bf16x8*)fAp;
      const bf16x8 fb0 = *(const bf16x8*)fBp;
      const bf16x8 fa1 = *(const bf16x8*)(fAp + 16);
      const bf16x8 fb1 = *(const bf16x8*)(fBp + 16);
      acc = __builtin_amdgcn_mfma_f32_32x32x16_bf16(fa0, fb0, acc, 0, 0, 0);
      acc = __builtin_amdgcn_mfma_f32_32x32x16_bf16(fa1, fb1, acc, 0, 0, 0);
    }

    pa += __shfl_xor(pa, 1, 64); pa += __shfl_xor(pa, 2, 64);
    pb += __shfl_xor(pb, 1, 64); pb += __shfl_xor(pb, 2, 64);
    if (sq == 0) {
      rA[sr] = 1.0f / fmaxf(sqrtf(pa), 1e-8f);
      rB[sr] = 1.0f / fmaxf(sqrtf(pb), 1e-8f);
    }
    __syncthreads();

    {
      const int rj = wj * 32 + ln;
      const float r2 = rB[rj];
#pragma unroll
      for (int reg = 0; reg < 16; ++reg) {
        const int ri = wi * 32 + (reg & 3) + 8 * (reg >> 2) + 4 * kh;
        sC[ri * CST + rj] = 1.0f - acc[reg] * rA[ri] * r2;
      }
    }
    __syncthreads();

    // diag stores in pair-interleaved layout: wave w rows r = w, w+4, ..., w+124
    {
      const int d0 = i0 + j0;
      const int a65 = 65 * lane;
#pragma unroll 4
      for (int rr = 0; rr < 32; ++rr) {
        const int r = 4 * rr + w;
        const int d = d0 + r;
        const int pp = d & 1;
        const int roff = ((d + pp - 50) >> 1) - i0;
        const int ri = lane + roff;
        const int rj = r - ri;
        const int kband = 2 * lane + pp;
        const int jg = j0 + rj;
        if (((unsigned)ri < 64u) & ((unsigned)rj < 64u) & (kband <= 100) &
            ((unsigned)jg < (unsigned)TT)) {
          db[(size_t)(1 + ((d - 1) >> 1)) * 128 + 2 * lane + ((d - 1) & 1)] =
              sC[a65 + 65 * roff + r];
        }
      }
    }

    // tile done: __syncthreads drains all waves' stores (vmcnt(0) before s_barrier),
    // then RELEASE the tile for batch b (agent scope -> cross-XCD visible).
    __syncthreads();
    if (t == 0)
      __hip_atomic_fetch_add(cnt + b, 1u, __ATOMIC_RELEASE, __HIP_MEMORY_SCOPE_AGENT);
  }
}

extern "C" void kernel_launch(void* const* d_in, const int* in_sizes, int n_in,
                              void* d_out, int out_size, void* d_ws, size_t ws_size,
                              hipStream_t stream) {
  const float* x1 = (const float*)d_in[0];
  const float* x2 = (const float*)d_in[1];
  float* out = (float*)d_out;
  float* diag = (float*)d_ws;  // 64 * 580 * 128 floats = 18.2 MB
  unsigned* cnt = (unsigned*)((char*)d_ws + CNT_OFF);  // 64 per-batch tile counters

  hipMemsetAsync(cnt, 0, NDP * sizeof(unsigned), stream);  // capture-safe
  dtw_fused<<<NDP + NPROD, 256, 0, stream>>>(x1, x2, diag, cnt, out);
}

// Round 9
// 187.149 us; speedup vs baseline: 1.0052x; 1.0052x over previous
//
#include <hip/hip_runtime.h>

#define BIGF 1e9f
#define TT 512
#define DD 256
#define NB 64
#define PROWS 580     // per-batch pair-rows (1 d0-row + 511 pairs + 32 prefetch pad + slack)
#define SAK 40        // LDS row stride in bf16 (32 data + 8 pad)
#define CST 66        // C-tile LDS stride in floats
#define NDP 64        // consumer (DP) blocks, blockIdx 0..63
#define NPROD 768     // producer blocks, 2 tiles each
#define CNT_OFF (20 * 1024 * 1024)  // counters past diag (18.2 MB) in the 256 MiB ws

typedef float floatx16 __attribute__((ext_vector_type(16)));
typedef __bf16 bf16x8 __attribute__((ext_vector_type(8)));

// ---------- DPP wave shifts: lane i <- lane i-1 (shr) / lane i+1 (shl); invalid lanes get `oldv`
__device__ __forceinline__ float dpp_wave_shr1(float x, float oldv) {
  int r = __builtin_amdgcn_update_dpp(__builtin_bit_cast(int, oldv),
                                      __builtin_bit_cast(int, x),
                                      0x138, 0xF, 0xF, false);  // WAVE_SHR1
  return __builtin_bit_cast(float, r);
}
__device__ __forceinline__ float dpp_wave_shl1(float x, float oldv) {
  int r = __builtin_amdgcn_update_dpp(__builtin_bit_cast(int, oldv),
                                      __builtin_bit_cast(int, x),
                                      0x130, 0xF, 0xF, false);  // WAVE_SHL1
  return __builtin_bit_cast(float, r);
}

// ---------- pair-interleaved band layout (round-7 verified) ----------
// Cell (d, k) [k = i-j+50, k and d share parity]:
//   row = 1 + ((d-1)>>1); off = row*128 + 2*(k>>1) + ((d-1)&1)
// Pair row p>=1 holds d=2p-1 (even comps) and d=2p (odd comps): one float2 at 2l gives
// lane l both its band cells. d=0 cell (0,0) -> off 51.

// ---------- Fused kernel: 768 producers + 64 DP consumers, one launch ----------
// ROUND-8 RETRY, spill mechanism fixed. Round 3/8 both compiled to 52-56 VGPR: with
// 17408 B LDS the backend's occupancy heuristic sees 8 blocks/CU achievable -> targets
// 8 waves/SIMD -> register budget 512/8 = 64 VGPR -> both code paths spill to scratch
// (producer needs ~100, consumer ~90) -> ~3x slowdown. __launch_bounds__(,1) only sets
// the MIN waves/EU; it does not stop that heuristic.
// FIX: inflate LDS to 36 KB (sPad) -> LDS-derived occupancy 4 blocks/CU = 4 waves/SIMD
// -> RA budget 128 VGPR -> no spill. 4 blocks/CU x 256 CU = 1024 slots >= 832 blocks:
// all co-resident, deadlock-free (producers never wait; consumers can't starve them).
__global__ __launch_bounds__(256, 1) void dtw_fused(const float* __restrict__ x1,
                                                    const float* __restrict__ x2,
                                                    float* __restrict__ diag,
                                                    unsigned* __restrict__ cnt,
                                                    float* __restrict__ out) {
  __shared__ __align__(16) float sC[64 * CST];
  __shared__ float sPad[4864];  // occupancy governor: total LDS 36864 B -> 4 blocks/CU
  if (threadIdx.x == 0) sPad[0] = 0.f;  // keep allocation live (never read)

  if (blockIdx.x < NDP) {
    // ================= DP consumer =================
    if (threadIdx.x >= 64) return;  // single wave; no __syncthreads on this path
    const int b = blockIdx.x;       // blockIdx%8 == b%8 -> same XCD as batch b's producers
    const int l = threadIdx.x;

    while (__hip_atomic_load(cnt + b, __ATOMIC_RELAXED, __HIP_MEMORY_SCOPE_AGENT) != 24u)
      __builtin_amdgcn_s_sleep(8);
    __builtin_amdgcn_fence(__ATOMIC_ACQUIRE, "agent");

    const bool inv_odd = (l >= 50);   // k=2l+1 > 100
    const bool inv_even = (l >= 51);  // k=2l   > 100
    const float* base = diag + (size_t)b * (PROWS * 128);

    const float* pP = base + 128 + 2 * l;  // pair 0 (d=1,2), lane slot
    float2 cr[32];                         // 32 pairs = 64 diagonals buffered (64 VGPR)
#pragma unroll
    for (int s = 0; s < 32; ++s) {
      cr[s] = *(const float2*)pP;
      pP += 128;
    }

    float prev2 = BIGF;
    const float c00 = base[51];  // cell (0,0)
    float prev1 = (l == 25) ? c00 : BIGF;
    float ans = BIGF;

    for (int o = 0; o < 16; ++o) {
#pragma unroll
      for (int u = 0; u < 32; ++u) {  // pair p = 32*o + u; static slot index (rule #20)
        const float2 v = cr[u];
        cr[u] = *(const float2*)pP;   // prefetch pair p+32 (max row 544 < PROWS, in-batch)
        pP += 128;
        // odd diagonal d = 2p+1
        const float c1 = inv_odd ? BIGF : v.x;
        const float sh = dpp_wave_shl1(prev1, BIGF);
        const float m3 = fminf(fminf(prev1, sh), prev2);
        prev2 = prev1;
        prev1 = c1 + m3;
        // even diagonal d = 2p+2
        const float c2 = inv_even ? BIGF : v.y;
        const float sh2 = dpp_wave_shr1(prev1, BIGF);
        const float m32 = fminf(fminf(sh2, prev1), prev2);
        prev2 = prev1;
        prev1 = c2 + m32;
        if (o == 15 && u == 30) ans = prev1;  // pair 510 even step -> d=1022, cell (511,511)
        // pair 511 consumed after ans; poison/paint values finite -> harmless
      }
    }
    if (l == 25) out[b] = ans;
    return;
  }

  // ================= producer (round-7 cost path verbatim) =================
  const int p = blockIdx.x - NDP;  // 0..767
  const int x = p & 7;             // XCD affinity heuristic (perf only)
  const int pl = p >> 3;           // 0..95 within XCD

  __bf16* sA = (__bf16*)sC;
  __bf16* sB = ((__bf16*)sC) + 64 * SAK;
  __shared__ float rA[64];
  __shared__ float rB[64];

  const int t = threadIdx.x;
  const int lane = t & 63;
  const int w = t >> 6;
  const int wi = w >> 1;
  const int wj = w & 1;
  const int ln = lane & 31;
  const int kh = lane >> 5;

  const int sr = t >> 2;
  const int sq = t & 3;
  __bf16* dA = sA + sr * SAK + sq * 8;
  __bf16* dB = sB + sr * SAK + sq * 8;
  const __bf16* fAp = sA + (wi * 32 + ln) * SAK + kh * 8;
  const __bf16* fBp = sB + (wj * 32 + ln) * SAK + kh * 8;

  for (int kt = 0; kt < 2; ++kt) {
    const int T = pl + 96 * kt;     // 0..191, batch-major within XCD
    const int bhi = T / 24;
    const int m = T - bhi * 24;
    const int b = bhi * 8 + x;
    const int it = m & 7;
    const int jt = m >> 3;
    const int i0 = it * 64;
    const int j0 = i0 - 50 + jt * 64;

    float* db = diag + (size_t)b * (PROWS * 128);

    // corner paint: consumed-but-unwritten cells of d in [1,64) U [972,1025) get BIG
    if (m == 0) {
      for (int r = w; r < 116; r += 4) {
        const int d = (r < 63) ? (r + 1) : (909 + r);  // 1..63, 972..1024
        const int pp = d & 1;
        const int k = 2 * lane + pp;
        const int i = (d + k - 50) >> 1;
        const int j = d - i;
        if (k > 100 || (unsigned)i >= TT || (unsigned)j >= TT)
          db[(size_t)(1 + ((d - 1) >> 1)) * 128 + 2 * lane + ((d - 1) & 1)] = BIGF;
      }
    }

    const float* x1b = x1 + (size_t)b * (TT * DD);
    const float* x2b = x2 + (size_t)b * (TT * DD);
    int gj = j0 + sr;
    gj = gj < 0 ? 0 : (gj > TT - 1 ? TT - 1 : gj);
    const float* pAg = x1b + (size_t)(i0 + sr) * DD + sq * 8;
    const float* pBg = x2b + (size_t)gj * DD + sq * 8;

    floatx16 acc = {};
    float pa = 0.f, pb = 0.f;

    for (int kc = 0; kc < DD; kc += 32) {
      const float4 a0 = *(const float4*)(pAg + kc);
      const float4 a1 = *(const float4*)(pAg + kc + 4);
      const float4 b0 = *(const float4*)(pBg + kc);
      const float4 b1 = *(const float4*)(pBg + kc + 4);
      pa += a0.x * a0.x + a0.y * a0.y + a0.z * a0.z + a0.w * a0.w;
      pa += a1.x * a1.x + a1.y * a1.y + a1.z * a1.z + a1.w * a1.w;
      pb += b0.x * b0.x + b0.y * b0.y + b0.z * b0.z + b0.w * b0.w;
      pb += b1.x * b1.x + b1.y * b1.y + b1.z * b1.z + b1.w * b1.w;
      // barrier also fences the previous tile's sC reads before sA/sB overwrite (alias)
      __syncthreads();
      {
        bf16x8 va, vb;
        va[0] = (__bf16)a0.x; va[1] = (__bf16)a0.y; va[2] = (__bf16)a0.z; va[3] = (__bf16)a0.w;
        va[4] = (__bf16)a1.x; va[5] = (__bf16)a1.y; va[6] = (__bf16)a1.z; va[7] = (__bf16)a1.w;
        vb[0] = (__bf16)b0.x; vb[1] = (__bf16)b0.y; vb[2] = (__bf16)b0.z; vb[3] = (__bf16)b0.w;
        vb[4] = (__bf16)b1.x; vb[5] = (__bf16)b1.y; vb[6] = (__bf16)b1.z; vb[7] = (__bf16)b1.w;
        *(bf16x8*)dA = va;
        *(bf16x8*)dB = vb;
      }
      __syncthreads();
      const bf16x8 fa0 = *(const bf16x8*)fAp;
      const bf16x8 fb0 = *(const bf16x8*)fBp;
      const bf16x8 fa1 = *(const bf16x8*)(fAp + 16);
      const bf16x8 fb1 = *(const bf16x8*)(fBp + 16);
      acc = __builtin_amdgcn_mfma_f32_32x32x16_bf16(fa0, fb0, acc, 0, 0, 0);
      acc = __builtin_amdgcn_mfma_f32_32x32x16_bf16(fa1, fb1, acc, 0, 0, 0);
    }

    pa += __shfl_xor(pa, 1, 64); pa += __shfl_xor(pa, 2, 64);
    pb += __shfl_xor(pb, 1, 64); pb += __shfl_xor(pb, 2, 64);
    if (sq == 0) {
      rA[sr] = 1.0f / fmaxf(sqrtf(pa), 1e-8f);
      rB[sr] = 1.0f / fmaxf(sqrtf(pb), 1e-8f);
    }
    __syncthreads();

    {
      const int rj = wj * 32 + ln;
      const float r2 = rB[rj];
#pragma unroll
      for (int reg = 0; reg < 16; ++reg) {
        const int ri = wi * 32 + (reg & 3) + 8 * (reg >> 2) + 4 * kh;
        sC[ri * CST + rj] = 1.0f - acc[reg] * rA[ri] * r2;
      }
    }
    __syncthreads();

    // diag stores in pair-interleaved layout: wave w rows r = w, w+4, ..., w+124
    {
      const int d0 = i0 + j0;
      const int a65 = 65 * lane;
#pragma unroll 4
      for (int rr = 0; rr < 32; ++rr) {
        const int r = 4 * rr + w;
        const int d = d0 + r;
        const int pp = d & 1;
        const int roff = ((d + pp - 50) >> 1) - i0;
        const int ri = lane + roff;
        const int rj = r - ri;
        const int kband = 2 * lane + pp;
        const int jg = j0 + rj;
        if (((unsigned)ri < 64u) & ((unsigned)rj < 64u) & (kband <= 100) &
            ((unsigned)jg < (unsigned)TT)) {
          db[(size_t)(1 + ((d - 1) >> 1)) * 128 + 2 * lane + ((d - 1) & 1)] =
              sC[a65 + 65 * roff + r];
        }
      }
    }

    // tile done: __syncthreads drains all waves' stores (vmcnt(0) before s_barrier),
    // then RELEASE the tile for batch b (agent scope -> cross-XCD visible).
    __syncthreads();
    if (t == 0)
      __hip_atomic_fetch_add(cnt + b, 1u, __ATOMIC_RELEASE, __HIP_MEMORY_SCOPE_AGENT);
  }
}

extern "C" void kernel_launch(void* const* d_in, const int* in_sizes, int n_in,
                              void* d_out, int out_size, void* d_ws, size_t ws_size,
                              hipStream_t stream) {
  const float* x1 = (const float*)d_in[0];
  const float* x2 = (const float*)d_in[1];
  float* out = (float*)d_out;
  float* diag = (float*)d_ws;  // 64 * 580 * 128 floats = 18.2 MB
  unsigned* cnt = (unsigned*)((char*)d_ws + CNT_OFF);  // 64 per-batch tile counters

  hipMemsetAsync(cnt, 0, NDP * sizeof(unsigned), stream);  // capture-safe
  dtw_fused<<<NDP + NPROD, 256, 0, stream>>>(x1, x2, diag, cnt, out);
}

// Round 10
// 127.497 us; speedup vs baseline: 1.4755x; 1.4679x over previous
//
#include <hip/hip_runtime.h>

#define BIGF 1e9f
#define TT 512
#define DD 256
#define NB 64
#define PROWS 580     // per-batch pair-rows (1 d0-row + 511 pairs + 64 prefetch pad + slack)
#define SAK 40        // LDS row stride in bf16 (32 data + 8 pad)
#define CST 66        // C-tile LDS stride in floats

typedef float floatx16 __attribute__((ext_vector_type(16)));
typedef __bf16 bf16x8 __attribute__((ext_vector_type(8)));

// ---------- DPP wave shifts: lane i <- lane i-1 (shr) / lane i+1 (shl); invalid lanes get `oldv`
__device__ __forceinline__ float dpp_wave_shr1(float x, float oldv) {
  int r = __builtin_amdgcn_update_dpp(__builtin_bit_cast(int, oldv),
                                      __builtin_bit_cast(int, x),
                                      0x138, 0xF, 0xF, false);  // WAVE_SHR1
  return __builtin_bit_cast(float, r);
}
__device__ __forceinline__ float dpp_wave_shl1(float x, float oldv) {
  int r = __builtin_amdgcn_update_dpp(__builtin_bit_cast(int, oldv),
                                      __builtin_bit_cast(int, x),
                                      0x130, 0xF, 0xF, false);  // WAVE_SHL1
  return __builtin_bit_cast(float, r);
}

// ---------- pair-interleaved band layout ----------
// Cell (d, k) [k = i-j+50, k and d share parity] lives at:
//   row = 1 + ((d-1)>>1)   (arith shift: d=0 -> row 0)
//   off = row*128 + 2*(k>>1) + ((d-1)&1)
// So pair row p>=1 holds diag d=2p-1 in even components and d=2p in odd components:
// one float2 load at 2l gives lane l BOTH its band cells (k=2l+1 odd-d, k=2l even-d)
// with NO cross-lane redistribution. d=0 cell (0,0) lands at off 51 via the same formula.

// ---------- Kernel B: banded cost via bf16 MFMA + fused norms ----------
// 768 persistent blocks (2 tiles each), batch-major per XCD (b%8 == blockIdx%8 heuristic):
// an XCD's concurrent working set ~4 batches ~4 MB -> L2-resident. 64x64 (i,j) tile per
// block; 4 waves 2x2; 32x32x16 bf16 MFMA K-loop with fused sum-of-squares; epilogue scales
// by 1/(||a|| ||b||), transposes through LDS (stride-65, conflict-free) and stores diag rows
// coalesced in the pair-interleaved layout. m==0 tiles BIG-paint corner-invalid cells.
__global__ __launch_bounds__(256) void cost_kernel(const float* __restrict__ x1,
                                                   const float* __restrict__ x2,
                                                   float* __restrict__ diag) {
  const int p = blockIdx.x;   // 0..767
  const int x = p & 7;        // XCD
  const int pl = p >> 3;      // 0..95 within XCD

  __shared__ __align__(16) float sC[64 * CST];
  __bf16* sA = (__bf16*)sC;
  __bf16* sB = ((__bf16*)sC) + 64 * SAK;
  __shared__ float rA[64];
  __shared__ float rB[64];

  const int t = threadIdx.x;
  const int lane = t & 63;
  const int w = t >> 6;
  const int wi = w >> 1;
  const int wj = w & 1;
  const int ln = lane & 31;
  const int kh = lane >> 5;

  const int sr = t >> 2;
  const int sq = t & 3;
  __bf16* dA = sA + sr * SAK + sq * 8;
  __bf16* dB = sB + sr * SAK + sq * 8;
  const __bf16* fAp = sA + (wi * 32 + ln) * SAK + kh * 8;
  const __bf16* fBp = sB + (wj * 32 + ln) * SAK + kh * 8;

  for (int kt = 0; kt < 2; ++kt) {
    const int T = pl + 96 * kt;     // 0..191, batch-major within XCD
    const int bhi = T / 24;
    const int m = T - bhi * 24;
    const int b = bhi * 8 + x;
    const int it = m & 7;
    const int jt = m >> 3;
    const int i0 = it * 64;
    const int j0 = i0 - 50 + jt * 64;

    float* db = diag + (size_t)b * (PROWS * 128);

    // corner paint: consumed-but-unwritten cells of d in [1,64) U [972,1025) get BIG.
    if (m == 0) {
      for (int r = w; r < 116; r += 4) {
        const int d = (r < 63) ? (r + 1) : (909 + r);  // 1..63, 972..1024
        const int pp = d & 1;
        const int k = 2 * lane + pp;
        const int i = (d + k - 50) >> 1;  // even numerator, exact
        const int j = d - i;
        if (k > 100 || (unsigned)i >= TT || (unsigned)j >= TT)
          db[(size_t)(1 + ((d - 1) >> 1)) * 128 + 2 * lane + ((d - 1) & 1)] = BIGF;
      }
    }

    const float* x1b = x1 + (size_t)b * (TT * DD);
    const float* x2b = x2 + (size_t)b * (TT * DD);
    int gj = j0 + sr;
    gj = gj < 0 ? 0 : (gj > TT - 1 ? TT - 1 : gj);
    const float* pAg = x1b + (size_t)(i0 + sr) * DD + sq * 8;
    const float* pBg = x2b + (size_t)gj * DD + sq * 8;

    floatx16 acc = {};
    float pa = 0.f, pb = 0.f;

    for (int kc = 0; kc < DD; kc += 32) {
      const float4 a0 = *(const float4*)(pAg + kc);
      const float4 a1 = *(const float4*)(pAg + kc + 4);
      const float4 b0 = *(const float4*)(pBg + kc);
      const float4 b1 = *(const float4*)(pBg + kc + 4);
      pa += a0.x * a0.x + a0.y * a0.y + a0.z * a0.z + a0.w * a0.w;
      pa += a1.x * a1.x + a1.y * a1.y + a1.z * a1.z + a1.w * a1.w;
      pb += b0.x * b0.x + b0.y * b0.y + b0.z * b0.z + b0.w * b0.w;
      pb += b1.x * b1.x + b1.y * b1.y + b1.z * b1.z + b1.w * b1.w;
      __syncthreads();
      {
        bf16x8 va, vb;
        va[0] = (__bf16)a0.x; va[1] = (__bf16)a0.y; va[2] = (__bf16)a0.z; va[3] = (__bf16)a0.w;
        va[4] = (__bf16)a1.x; va[5] = (__bf16)a1.y; va[6] = (__bf16)a1.z; va[7] = (__bf16)a1.w;
        vb[0] = (__bf16)b0.x; vb[1] = (__bf16)b0.y; vb[2] = (__bf16)b0.z; vb[3] = (__bf16)b0.w;
        vb[4] = (__bf16)b1.x; vb[5] = (__bf16)b1.y; vb[6] = (__bf16)b1.z; vb[7] = (__bf16)b1.w;
        *(bf16x8*)dA = va;
        *(bf16x8*)dB = vb;
      }
      __syncthreads();
      const bf16x8 fa0 = *(const bf16x8*)fAp;
      const bf16x8 fb0 = *(const bf16x8*)fBp;
      const bf16x8 fa1 = *(const bf16x8*)(fAp + 16);
      const bf16x8 fb1 = *(const bf16x8*)(fBp + 16);
      acc = __builtin_amdgcn_mfma_f32_32x32x16_bf16(fa0, fb0, acc, 0, 0, 0);
      acc = __builtin_amdgcn_mfma_f32_32x32x16_bf16(fa1, fb1, acc, 0, 0, 0);
    }

    pa += __shfl_xor(pa, 1, 64); pa += __shfl_xor(pa, 2, 64);
    pb += __shfl_xor(pb, 1, 64); pb += __shfl_xor(pb, 2, 64);
    if (sq == 0) {
      rA[sr] = 1.0f / fmaxf(sqrtf(pa), 1e-8f);
      rB[sr] = 1.0f / fmaxf(sqrtf(pb), 1e-8f);
    }
    __syncthreads();

    {
      const int rj = wj * 32 + ln;
      const float r2 = rB[rj];
#pragma unroll
      for (int reg = 0; reg < 16; ++reg) {
        const int ri = wi * 32 + (reg & 3) + 8 * (reg >> 2) + 4 * kh;
        sC[ri * CST + rj] = 1.0f - acc[reg] * rA[ri] * r2;
      }
    }
    __syncthreads();

    // diag stores: wave w handles tile-diag rows r = w, w+4, ..., w+124 (d = d0 + r).
    // lane l holds band cell k = 2l + (d&1) via the LDS transpose (stride-65, conflict-free);
    // global: 64 lanes at float stride 2 -> 512 B span per row store.
    {
      const int d0 = i0 + j0;
      const int a65 = 65 * lane;
#pragma unroll 4
      for (int rr = 0; rr < 32; ++rr) {
        const int r = 4 * rr + w;
        const int d = d0 + r;
        const int pp = d & 1;
        const int roff = ((d + pp - 50) >> 1) - i0;
        const int ri = lane + roff;
        const int rj = r - ri;
        const int kband = 2 * lane + pp;
        const int jg = j0 + rj;
        if (((unsigned)ri < 64u) & ((unsigned)rj < 64u) & (kband <= 100) &
            ((unsigned)jg < (unsigned)TT)) {
          db[(size_t)(1 + ((d - 1) >> 1)) * 128 + 2 * lane + ((d - 1) & 1)] =
              sC[a65 + 65 * roff + r];
        }
      }
    }
  }
}

// ---------- Kernel C: DP with float2 rolling prefetch, zero-shuffle ----------
// Single wave per batch, no barriers. Lane l loads float2 at pair row p, offset 2l:
// v.x = cell k=2l+1 of d=2p+1, v.y = cell k=2l of d=2p+2 -- directly in band layout,
// no cross-lane ops. 63 in-flight float2 loads cover ~126 diagonals under the 6-bit
// vmcnt cap; chain = dpp + min3 + add per diagonal.
__global__ __launch_bounds__(64, 1) void dtw_dp_kernel(const float* __restrict__ diag,
                                                       float* __restrict__ out) {
  const int b = blockIdx.x;
  const int l = threadIdx.x;
  const bool inv_odd = (l >= 50);   // k=2l+1 > 100
  const bool inv_even = (l >= 51);  // k=2l   > 100
  const float* base = diag + (size_t)b * (PROWS * 128);

  const float* pP = base + 128 + 2 * l;  // pair 0 (d=1,2), lane slot
  float2 cr[64];                         // 64 pairs = 128 diagonals buffered
#pragma unroll
  for (int s = 0; s < 64; ++s) {
    cr[s] = *(const float2*)pP;
    pP += 128;  // next pair row
  }

  float prev2 = BIGF;
  const float c00 = base[51];                 // cell (0,0): d=0 slot per layout formula
  float prev1 = (l == 25) ? c00 : BIGF;
  float ans = BIGF;

  for (int o = 0; o < 8; ++o) {
#pragma unroll
    for (int u = 0; u < 64; ++u) {   // pair p = 64*o + u; slot index static (rule #20)
      const float2 v = cr[u];
      cr[u] = *(const float2*)pP;    // prefetch pair p+64 (max row 576 < PROWS, in-batch)
      pP += 128;
      // odd diagonal d = 2p+1
      const float c1 = inv_odd ? BIGF : v.x;
      const float sh = dpp_wave_shl1(prev1, BIGF);
      const float m3 = fminf(fminf(prev1, sh), prev2);
      prev2 = prev1;
      prev1 = c1 + m3;
      // even diagonal d = 2p+2
      const float c2 = inv_even ? BIGF : v.y;
      const float sh2 = dpp_wave_shr1(prev1, BIGF);
      const float m32 = fminf(fminf(sh2, prev1), prev2);
      prev2 = prev1;
      prev1 = c2 + m32;
      if (o == 7 && u == 62) ans = prev1;  // d = 1022 -> cell (511,511) at lane 25
      // pair 511 (d=1023,1024) consumed after ans; values irrelevant (finite)
    }
  }
  if (l == 25) out[b] = ans;
}

extern "C" void kernel_launch(void* const* d_in, const int* in_sizes, int n_in,
                              void* d_out, int out_size, void* d_ws, size_t ws_size,
                              hipStream_t stream) {
  const float* x1 = (const float*)d_in[0];
  const float* x2 = (const float*)d_in[1];
  float* out = (float*)d_out;
  float* diag = (float*)d_ws;  // 64 * 580 * 128 floats = 19.0 MB

  cost_kernel<<<768, 256, 0, stream>>>(x1, x2, diag);
  dtw_dp_kernel<<<NB, 64, 0, stream>>>(diag, out);
}